// Round 6
// baseline (108.238 us; speedup 1.0000x reference)
//
#include <hip/hip_runtime.h>
#include <math.h>

#define PMAX 22
#define HID 64
#define OUTD 128
#define SETS_PER_WAVE 4
#define WAVES_PER_BLOCK 4

typedef __attribute__((ext_vector_type(4))) float float4v;
typedef _Float16 fh2 __attribute__((ext_vector_type(2)));
typedef _Float16 half8 __attribute__((ext_vector_type(8)));

__device__ __forceinline__ int rl_i(int v, int l) {
    return __builtin_amdgcn_readlane(v, l);
}
// pack two fp32 -> f16x2 bits (v_cvt_pkrtz_f16_f32)
__device__ __forceinline__ int pk2(float x, float y) {
    auto v = __builtin_amdgcn_cvt_pkrtz(x, y);
    union { decltype(v) h; int i; } c;
    c.h = v;
    return c.i;
}
// fp32 -> f16 bits (low half of pkrtz)
__device__ __forceinline__ unsigned short f16b(float x) {
    return (unsigned short)(pk2(x, x) & 0xFFFF);
}
// f16x2 dot-product accumulate: c += a.x*b.x + a.y*b.y (v_dot2_f32_f16)
__device__ __forceinline__ float fdot2i(int a, int b, float c) {
    union { int i; fh2 h; } ua, ub;
    ua.i = a;
    ub.i = b;
#if defined(__has_builtin) && __has_builtin(__builtin_amdgcn_fdot2)
    return __builtin_amdgcn_fdot2(ua.h, ub.h, c, false);
#else
    return fmaf((float)ua.h.x, (float)ub.h.x, fmaf((float)ua.h.y, (float)ub.h.y, c));
#endif
}
// Wave-internal LDS sync (per-wave hb slice only).
__device__ __forceinline__ void wave_lds_sync() {
    asm volatile("s_waitcnt lgkmcnt(0)" ::: "memory");
    __builtin_amdgcn_wave_barrier();
}
// Fast atan2: |err| ~1e-4 rad. Degree-7 odd minimax on [0,1].
__device__ __forceinline__ float fast_atan2(float y, float x) {
    float ax = fabsf(x), ay = fabsf(y);
    float mn = fminf(ax, ay), mx = fmaxf(ax, ay);
    float a = mn * __builtin_amdgcn_rcpf(fmaxf(mx, 1e-30f));
    float s = a * a;
    float r = a * fmaf(s, fmaf(s, fmaf(s, -0.0851330f, 0.1801410f), -0.3302995f), 0.9998660f);
    if (ay > ax) r = 1.57079637f - r;
    if (x < 0.0f) r = 3.14159274f - r;
    return copysignf(r, y);
}

// 4 sets/wave -> 4096 blocks -> TWO residency rounds (2048 blocks was exactly
// one round: global phase lockstep, reads/VALU/writes serialized machine-wide).
// Round 2's input reads now overlap round 1's MFMA+stores.
__global__ __launch_bounds__(256, 8) void set_encoder_kernel(
    const float* __restrict__ player_locs,  // [B,22,2]
    const float* __restrict__ actor_locs,   // [B,2]
    const float* __restrict__ flags,        // [B,22,2]
    const int*   __restrict__ mask,         // [B,22]
    const float* __restrict__ W1,           // [6,64]
    const float* __restrict__ b1,           // [64]
    const float* __restrict__ W2,           // [64,128]
    const float* __restrict__ b2,           // [128]
    float* __restrict__ out)                // [B,128]
{
    // B-fragments of W2 as f16 pairs. 16B-unit index XOR-swizzled by n-tile id
    // (u^nt): staging ds_write_b32 banks spread 32-wide, MFMA-side b128 read
    // stays a bijective permutation of a linear 1KB burst (conflict-free).
    __shared__ __align__(16) unsigned w2f[16 * 256];                        // 16 KB
    // h-bar f16, [wave][set][hid]; unpadded. Total LDS 18432 B -> 8 blocks/CU.
    __shared__ __align__(16) unsigned short hb[WAVES_PER_BLOCK][SETS_PER_WAVE][64];

    const int tid  = threadIdx.x;
    const int lane = tid & 63;
    const int wave = tid >> 6;

    const int wave_id = blockIdx.x * WAVES_PER_BLOCK + wave;
    const int set0    = wave_id * SETS_PER_WAVE;

    // --- W2 -> LDS staging, tight ra/rb live range ---
    {
        const int pr  = tid >> 3;   // k-pair 0..31 (rows 2pr, 2pr+1)
        const int nt8 = tid & 7;    // n-tile 0..7
        float ra[16], rb[16];
        const float* rA = W2 + (size_t)(2 * pr) * OUTD + 16 * nt8;
        const float* rB = rA + OUTD;
#pragma unroll
        for (int i = 0; i < 4; ++i) {
            *(float4*)&ra[4 * i] = ((const float4*)rA)[i];
            *(float4*)&rb[4 * i] = ((const float4*)rB)[i];
        }
        const int kt = pr >> 4;
        const int kk = (2 * pr) & 31;
        const int Qs = kk >> 3;
        const int j2 = (kk >> 1) & 3;
        const int tb = (kt * 8 + nt8) * 256;
#pragma unroll
        for (int c = 0; c < 16; ++c) {
            const int u = (Qs * 16 + c) ^ nt8;  // swizzled 16B-unit index
            w2f[tb + u * 4 + j2] = pk2(ra[c], rb[c]);  // (k even, k odd) pair
        }
    }
    // Fence the scheduler: nothing below may hoist into the ra/rb window.
    __builtin_amdgcn_sched_barrier(0);

    // --- raw inputs for this wave's 4 sets, issued pre-barrier: all waves
    //     drain their loads concurrently inside __syncthreads' vmcnt(0). ---
    const int lidx = lane < 2 * PMAX ? lane : 2 * PMAX - 1;  // clamp
    float2 pl[2], fl[2], ac2[2];
    int    mk[2];
    {
        const size_t r0 = (size_t)set0 * PMAX + lidx;
        const float2* plb = (const float2*)player_locs + r0;
        const float2* flb = (const float2*)flags + r0;
        const int*    mkb = mask + r0;
        const float2* acb = (const float2*)actor_locs + set0 + (lidx >= PMAX ? 1 : 0);
#pragma unroll
        for (int g = 0; g < 2; ++g) {
            pl[g]  = plb[g * 2 * PMAX];
            fl[g]  = flb[g * 2 * PMAX];
            mk[g]  = mkb[g * 2 * PMAX];
            ac2[g] = acb[2 * g];
        }
    }

    // --- per-lane W1 column + bias, packed f16x2 (lane = hidden unit) ---
    const int w01 = pk2(W1[0 * HID + lane], W1[1 * HID + lane]);
    const int w23 = pk2(W1[2 * HID + lane], W1[3 * HID + lane]);
    const int w45 = pk2(W1[4 * HID + lane], W1[5 * HID + lane]);
    const float b1l = b1[lane];

    // lane geometry: A rows dup with period 4 (sA = lane&3), so acc reg r of
    // EVERY lane quad Q is set r. nh (lane>>5) picks the nt half; the two
    // Q-groups within an nh half store identical values to identical addrs
    // (benign same-value collision), keeping 16 wide stores per wave.
    const int c15 = lane & 15;
    const int Q   = lane >> 4;
    const int sA  = lane & 3;
    const int nh  = lane >> 5;
    float b2v[4];
#pragma unroll
    for (int k = 0; k < 4; ++k) b2v[k] = b2[64 * nh + 16 * k + c15];

    __syncthreads();  // w2f visible to all waves (only block barrier)

    // --- phase 0: features for 4 sets (2 per iter, lanes 0..43) into f16x2;
    //     validity bitmap moved to SGPRs via readfirstlane (wave-uniform). ---
    int fh[2][3];
    unsigned long long wbm[2];  // scalar 44-bit window per set-pair
#pragma unroll
    for (int g = 0; g < 2; ++g) {
        float dx = pl[g].x - ac2[g].x;
        float dy = pl[g].y - ac2[g].y;
        float dist = __builtin_amdgcn_sqrtf(fmaf(dx, dx, dy * dy));
        float ang  = fast_atan2(dy, dx);
        fh[g][0] = pk2(dx, dy);
        fh[g][1] = pk2(dist, ang);
        fh[g][2] = pk2(fl[g].x, fl[g].y);
        unsigned long long bl = __ballot((lane < 2 * PMAX) && (mk[g] != 0));
        const unsigned lo = __builtin_amdgcn_readfirstlane((unsigned)bl);
        const unsigned hi = __builtin_amdgcn_readfirstlane((unsigned)(bl >> 32));
        wbm[g] = ((unsigned long long)hi << 32) | lo;  // uniform (SGPR pair)
    }

    // --- phase 1: layer1 + masked pool; lane = hidden unit.
    //     Fully unrolled p-loop; per player a UNIFORM scalar branch
    //     (s_bitcmp+s_cbranch) guards an 8-VALU body whose readlane index
    //     is a compile-time immediate. ---
    unsigned nonempty = 0;
#pragma unroll
    for (int s = 0; s < SETS_PER_WAVE; ++s) {
        const int g    = s >> 1;
        const int base = (s & 1) * PMAX;
        const unsigned bits = (unsigned)(wbm[g] >> base) & 0x3FFFFFu;  // uniform
        const int cnt = __builtin_popcount(bits);
        if (bits) nonempty |= (1u << s);
        float accv = 0.0f;
#pragma unroll
        for (int p = 0; p < PMAX; ++p) {
            if (bits & (1u << p)) {
                float t = fdot2i(rl_i(fh[g][0], base + p), w01, b1l);
                t = fdot2i(rl_i(fh[g][1], base + p), w23, t);
                t = fdot2i(rl_i(fh[g][2], base + p), w45, t);
                accv += fmaxf(t, 0.0f);
            }
        }
        // cnt <= 22; rcp rel-err ~1e-7 is far below the f16 round below.
        const float hbar = accv * __builtin_amdgcn_rcpf(fmaxf((float)cnt, 1.0f));
        hb[wave][s][lane] = f16b(hbar);
    }
    wave_lds_sync();

    // --- phase 2 + epilogue, fused per nt-pair: compute 4 MFMA then store
    //     immediately (8 live acc VGPRs; every index compile-time — the
    //     acc[8] dynamic-index scratch bug of rounds 1-3 cost +64MB writes). ---
    half8 afrag[2];
#pragma unroll
    for (int kt = 0; kt < 2; ++kt) {
        union { uint4 u4; half8 h8; } cv;
        cv.u4 = *(const uint4*)&hb[wave][sA][kt * 32 + Q * 8];  // aligned b128
        afrag[kt] = cv.h8;
    }

    float fs[4];
#pragma unroll
    for (int r = 0; r < 4; ++r) fs[r] = (float)((nonempty >> r) & 1u);

    float* obase = out + (size_t)set0 * OUTD + 64 * nh + c15;

#pragma unroll
    for (int j = 0; j < 4; ++j) {
        const int ntA = j;      // columns 16j..16j+15
        const int ntB = 4 + j;  // columns 64+16j..64+16j+15
        union { uint4 u4; half8 h8; } f0a, f1a, f0b, f1b;
        f0a.u4 = *(const uint4*)&w2f[(0 * 8 + ntA) * 256 + 4 * (lane ^ ntA)];
        f1a.u4 = *(const uint4*)&w2f[(1 * 8 + ntA) * 256 + 4 * (lane ^ ntA)];
        f0b.u4 = *(const uint4*)&w2f[(0 * 8 + ntB) * 256 + 4 * (lane ^ ntB)];
        f1b.u4 = *(const uint4*)&w2f[(1 * 8 + ntB) * 256 + 4 * (lane ^ ntB)];
        float4v z = {0.0f, 0.0f, 0.0f, 0.0f};
        float4v aA = __builtin_amdgcn_mfma_f32_16x16x32_f16(afrag[0], f0a.h8, z, 0, 0, 0);
        aA = __builtin_amdgcn_mfma_f32_16x16x32_f16(afrag[1], f1a.h8, aA, 0, 0, 0);
        float4v aB = __builtin_amdgcn_mfma_f32_16x16x32_f16(afrag[0], f0b.h8, z, 0, 0, 0);
        aB = __builtin_amdgcn_mfma_f32_16x16x32_f16(afrag[1], f1b.h8, aB, 0, 0, 0);
#pragma unroll
        for (int r = 0; r < 4; ++r) {
            const float v = nh ? aB[r] : aA[r];  // static extracts + cndmask
            obase[r * OUTD + 16 * j] = fmaf(fs[r], b2v[j], v);
        }
    }
}

extern "C" void kernel_launch(void* const* d_in, const int* in_sizes, int n_in,
                              void* d_out, int out_size, void* d_ws, size_t ws_size,
                              hipStream_t stream) {
    const float* player_locs = (const float*)d_in[0];
    const float* actor_locs  = (const float*)d_in[1];
    const float* flags       = (const float*)d_in[2];
    const int*   mask        = (const int*)d_in[3];
    const float* W1          = (const float*)d_in[4];
    const float* b1          = (const float*)d_in[5];
    const float* W2          = (const float*)d_in[6];
    const float* b2          = (const float*)d_in[7];
    float*       out         = (float*)d_out;

    const int B = in_sizes[0] / (PMAX * 2);  // 65536
    const int sets_per_block = WAVES_PER_BLOCK * SETS_PER_WAVE;  // 16
    const int grid = (B + sets_per_block - 1) / sets_per_block;  // 4096

    hipLaunchKernelGGL(set_encoder_kernel, dim3(grid), dim3(256), 0, stream,
                       player_locs, actor_locs, flags, mask, W1, b1, W2, b2, out);
}

// Round 7
// 106.022 us; speedup vs baseline: 1.0209x; 1.0209x over previous
//
#include <hip/hip_runtime.h>
#include <math.h>

#define PMAX 22
#define HID 64
#define OUTD 128
#define SETS_PER_WAVE 8
#define WAVES_PER_BLOCK 4

typedef __attribute__((ext_vector_type(4))) float float4v;
typedef _Float16 fh2 __attribute__((ext_vector_type(2)));
typedef _Float16 half8 __attribute__((ext_vector_type(8)));

__device__ __forceinline__ int rl_i(int v, int l) {
    return __builtin_amdgcn_readlane(v, l);
}
// pack two fp32 -> f16x2 bits (v_cvt_pkrtz_f16_f32)
__device__ __forceinline__ int pk2(float x, float y) {
    auto v = __builtin_amdgcn_cvt_pkrtz(x, y);
    union { decltype(v) h; int i; } c;
    c.h = v;
    return c.i;
}
// fp32 -> f16 bits (low half of pkrtz)
__device__ __forceinline__ unsigned short f16b(float x) {
    return (unsigned short)(pk2(x, x) & 0xFFFF);
}
// f16x2 dot-product accumulate: c += a.x*b.x + a.y*b.y (v_dot2_f32_f16)
__device__ __forceinline__ float fdot2i(int a, int b, float c) {
    union { int i; fh2 h; } ua, ub;
    ua.i = a;
    ub.i = b;
#if defined(__has_builtin) && __has_builtin(__builtin_amdgcn_fdot2)
    return __builtin_amdgcn_fdot2(ua.h, ub.h, c, false);
#else
    return fmaf((float)ua.h.x, (float)ub.h.x, fmaf((float)ua.h.y, (float)ub.h.y, c));
#endif
}
// Wave-internal LDS sync (per-wave hb slice only).
__device__ __forceinline__ void wave_lds_sync() {
    asm volatile("s_waitcnt lgkmcnt(0)" ::: "memory");
    __builtin_amdgcn_wave_barrier();
}
// Fast atan2: |err| ~1e-4 rad. Degree-7 odd minimax on [0,1].
__device__ __forceinline__ float fast_atan2(float y, float x) {
    float ax = fabsf(x), ay = fabsf(y);
    float mn = fminf(ax, ay), mx = fmaxf(ax, ay);
    float a = mn * __builtin_amdgcn_rcpf(fmaxf(mx, 1e-30f));
    float s = a * a;
    float r = a * fmaf(s, fmaf(s, fmaf(s, -0.0851330f, 0.1801410f), -0.3302995f), 0.9998660f);
    if (ay > ax) r = 1.57079637f - r;
    if (x < 0.0f) r = 3.14159274f - r;
    return copysignf(r, y);
}

// 2048 blocks x 4 waves = exactly one full residency round (8 blocks/CU,
// 32 waves/CU). Both alternatives measured WORSE: persistent 1024-block
// (r1: -TLP), 4096-block 2-round split (r6: 2x staging prologues).
__global__ __launch_bounds__(256, 8) void set_encoder_kernel(
    const float* __restrict__ player_locs,  // [B,22,2]
    const float* __restrict__ actor_locs,   // [B,2]
    const float* __restrict__ flags,        // [B,22,2]
    const int*   __restrict__ mask,         // [B,22]
    const float* __restrict__ W1,           // [6,64]
    const float* __restrict__ b1,           // [64]
    const float* __restrict__ W2,           // [64,128]
    const float* __restrict__ b2,           // [128]
    float* __restrict__ out)                // [B,128]
{
    // B-fragments of W2 as f16 pairs. 16B-unit index XOR-swizzled by n-tile id
    // (u^nt): staging ds_write_b32 banks spread 32-wide, MFMA-side b128 read
    // stays a bijective permutation of a linear 1KB burst (conflict-free).
    __shared__ __align__(16) unsigned w2f[16 * 256];                        // 16 KB
    // h-bar f16, [wave][set][hid]. Unpadded 64-short rows: total LDS exactly
    // 20480 B = 160KiB/8 -> 8 blocks/CU.
    __shared__ __align__(16) unsigned short hb[WAVES_PER_BLOCK][SETS_PER_WAVE][64];

    const int tid  = threadIdx.x;
    const int lane = tid & 63;
    const int wave = tid >> 6;

    const int wave_id = blockIdx.x * WAVES_PER_BLOCK + wave;
    const int set0    = wave_id * SETS_PER_WAVE;

    // --- W2 -> LDS staging, tight ra/rb live range (stretching it across
    //     other loads spilled 32 regs to scratch in r1-r3: +64MB HBM). ---
    {
        const int pr  = tid >> 3;   // k-pair 0..31 (rows 2pr, 2pr+1)
        const int nt8 = tid & 7;    // n-tile 0..7
        float ra[16], rb[16];
        const float* rA = W2 + (size_t)(2 * pr) * OUTD + 16 * nt8;
        const float* rB = rA + OUTD;
#pragma unroll
        for (int i = 0; i < 4; ++i) {
            *(float4*)&ra[4 * i] = ((const float4*)rA)[i];
            *(float4*)&rb[4 * i] = ((const float4*)rB)[i];
        }
        const int kt = pr >> 4;
        const int kk = (2 * pr) & 31;
        const int Qs = kk >> 3;
        const int j2 = (kk >> 1) & 3;
        const int tb = (kt * 8 + nt8) * 256;
#pragma unroll
        for (int c = 0; c < 16; ++c) {
            const int u = (Qs * 16 + c) ^ nt8;  // swizzled 16B-unit index
            w2f[tb + u * 4 + j2] = pk2(ra[c], rb[c]);  // (k even, k odd) pair
        }
    }
    // Fence the scheduler: nothing below may hoist into the ra/rb window.
    __builtin_amdgcn_sched_barrier(0);

    // --- raw inputs for this wave's 8 sets, issued pre-barrier: all waves
    //     drain their loads concurrently inside __syncthreads' vmcnt(0). ---
    const int lidx = lane < 2 * PMAX ? lane : 2 * PMAX - 1;  // clamp
    float2 pl[4], fl[4], ac2[4];
    int    mk[4];
    {
        const size_t r0 = (size_t)set0 * PMAX + lidx;
        const float2* plb = (const float2*)player_locs + r0;
        const float2* flb = (const float2*)flags + r0;
        const int*    mkb = mask + r0;
        const float2* acb = (const float2*)actor_locs + set0 + (lidx >= PMAX ? 1 : 0);
#pragma unroll
        for (int g = 0; g < 4; ++g) {
            pl[g]  = plb[g * 2 * PMAX];
            fl[g]  = flb[g * 2 * PMAX];
            mk[g]  = mkb[g * 2 * PMAX];
            ac2[g] = acb[2 * g];
        }
    }

    // --- per-lane W1 column + bias, packed f16x2 (lane = hidden unit) ---
    const int w01 = pk2(W1[0 * HID + lane], W1[1 * HID + lane]);
    const int w23 = pk2(W1[2 * HID + lane], W1[3 * HID + lane]);
    const int w45 = pk2(W1[4 * HID + lane], W1[5 * HID + lane]);
    const float b1l = b1[lane];

    // epilogue lane geometry: C rows 8..15 duplicate rows 0..7 (A rows dup),
    // so all 64 lanes store: sq picks the set-quad, nh picks the nt half.
    const int c15 = lane & 15;
    const int Q   = lane >> 4;
    const int sA  = lane & 7;
    const int sq  = Q & 1;
    const int nh  = lane >> 5;
    float b2v[4];
#pragma unroll
    for (int k = 0; k < 4; ++k) b2v[k] = b2[64 * nh + 16 * k + c15];

    __syncthreads();  // w2f visible to all waves (only block barrier)

    // --- phase 0: features for 8 sets (2 per iter, lanes 0..43) into f16x2;
    //     validity bitmap moved to SGPRs via readfirstlane (wave-uniform). ---
    int fh[4][3];
    unsigned long long wbm[4];  // scalar 44-bit window per set-pair
#pragma unroll
    for (int g = 0; g < 4; ++g) {
        float dx = pl[g].x - ac2[g].x;
        float dy = pl[g].y - ac2[g].y;
        float dist = __builtin_amdgcn_sqrtf(fmaf(dx, dx, dy * dy));
        float ang  = fast_atan2(dy, dx);
        fh[g][0] = pk2(dx, dy);
        fh[g][1] = pk2(dist, ang);
        fh[g][2] = pk2(fl[g].x, fl[g].y);
        unsigned long long bl = __ballot((lane < 2 * PMAX) && (mk[g] != 0));
        const unsigned lo = __builtin_amdgcn_readfirstlane((unsigned)bl);
        const unsigned hi = __builtin_amdgcn_readfirstlane((unsigned)(bl >> 32));
        wbm[g] = ((unsigned long long)hi << 32) | lo;  // uniform (SGPR pair)
    }

    // --- phase 1: layer1 + masked pool; lane = hidden unit.
    //     Fully unrolled p-loop; per player a UNIFORM scalar branch
    //     (s_bitcmp+s_cbranch) guards an 8-VALU body whose readlane index
    //     is a compile-time immediate. Dual accumulators (even/odd p) break
    //     the ~11-deep serial f32 add chain. ---
    unsigned nonempty = 0;
#pragma unroll
    for (int s = 0; s < SETS_PER_WAVE; ++s) {
        const int g    = s >> 1;
        const int base = (s & 1) * PMAX;
        const unsigned bits = (unsigned)(wbm[g] >> base) & 0x3FFFFFu;  // uniform
        const int cnt = __builtin_popcount(bits);
        if (bits) nonempty |= (1u << s);
        float acc0 = 0.0f, acc1 = 0.0f;
#pragma unroll
        for (int p = 0; p < PMAX; ++p) {
            if (bits & (1u << p)) {
                float t = fdot2i(rl_i(fh[g][0], base + p), w01, b1l);
                t = fdot2i(rl_i(fh[g][1], base + p), w23, t);
                t = fdot2i(rl_i(fh[g][2], base + p), w45, t);
                if (p & 1) acc1 += fmaxf(t, 0.0f);
                else       acc0 += fmaxf(t, 0.0f);
            }
        }
        const float accv = acc0 + acc1;
        // cnt <= 22; rcp rel-err ~1e-7 is far below the f16 round below.
        const float hbar = accv * __builtin_amdgcn_rcpf(fmaxf((float)cnt, 1.0f));
        hb[wave][s][lane] = f16b(hbar);
    }
    wave_lds_sync();

    // --- phase 2 + epilogue, fused per nt-pair: compute 4 MFMA then store
    //     immediately. 8 live acc VGPRs; every index compile-time (the
    //     acc[8] dynamic-index scratch bug of r1-r3 cost +64MB writes). ---
    half8 afrag[2];
#pragma unroll
    for (int kt = 0; kt < 2; ++kt) {
        union { uint4 u4; half8 h8; } cv;
        cv.u4 = *(const uint4*)&hb[wave][sA][kt * 32 + Q * 8];  // aligned b128
        afrag[kt] = cv.h8;
    }

    float fs[4];
#pragma unroll
    for (int r = 0; r < 4; ++r) fs[r] = (float)((nonempty >> (4 * sq + r)) & 1u);

    float* obase = out + (size_t)(set0 + 4 * sq) * OUTD + 64 * nh + c15;

#pragma unroll
    for (int j = 0; j < 4; ++j) {
        const int ntA = j;      // columns 16j..16j+15
        const int ntB = 4 + j;  // columns 64+16j..64+16j+15
        union { uint4 u4; half8 h8; } f0a, f1a, f0b, f1b;
        f0a.u4 = *(const uint4*)&w2f[(0 * 8 + ntA) * 256 + 4 * (lane ^ ntA)];
        f1a.u4 = *(const uint4*)&w2f[(1 * 8 + ntA) * 256 + 4 * (lane ^ ntA)];
        f0b.u4 = *(const uint4*)&w2f[(0 * 8 + ntB) * 256 + 4 * (lane ^ ntB)];
        f1b.u4 = *(const uint4*)&w2f[(1 * 8 + ntB) * 256 + 4 * (lane ^ ntB)];
        float4v z = {0.0f, 0.0f, 0.0f, 0.0f};
        float4v aA = __builtin_amdgcn_mfma_f32_16x16x32_f16(afrag[0], f0a.h8, z, 0, 0, 0);
        aA = __builtin_amdgcn_mfma_f32_16x16x32_f16(afrag[1], f1a.h8, aA, 0, 0, 0);
        float4v aB = __builtin_amdgcn_mfma_f32_16x16x32_f16(afrag[0], f0b.h8, z, 0, 0, 0);
        aB = __builtin_amdgcn_mfma_f32_16x16x32_f16(afrag[1], f1b.h8, aB, 0, 0, 0);
#pragma unroll
        for (int r = 0; r < 4; ++r) {
            const float v = nh ? aB[r] : aA[r];  // static extracts + cndmask
            obase[r * OUTD + 16 * j] = fmaf(fs[r], b2v[j], v);
        }
    }
}

extern "C" void kernel_launch(void* const* d_in, const int* in_sizes, int n_in,
                              void* d_out, int out_size, void* d_ws, size_t ws_size,
                              hipStream_t stream) {
    const float* player_locs = (const float*)d_in[0];
    const float* actor_locs  = (const float*)d_in[1];
    const float* flags       = (const float*)d_in[2];
    const int*   mask        = (const int*)d_in[3];
    const float* W1          = (const float*)d_in[4];
    const float* b1          = (const float*)d_in[5];
    const float* W2          = (const float*)d_in[6];
    const float* b2          = (const float*)d_in[7];
    float*       out         = (float*)d_out;

    const int B = in_sizes[0] / (PMAX * 2);  // 65536
    const int sets_per_block = WAVES_PER_BLOCK * SETS_PER_WAVE;  // 32
    const int grid = (B + sets_per_block - 1) / sets_per_block;  // 2048

    hipLaunchKernelGGL(set_encoder_kernel, dim3(grid), dim3(256), 0, stream,
                       player_locs, actor_locs, flags, mask, W1, b1, W2, b2, out);
}